// Round 7
// baseline (286.620 us; speedup 1.0000x reference)
//
#include <hip/hip_runtime.h>
#include <hip/hip_bf16.h>
#include <stdint.h>
#include <stddef.h>

#define GN 6144
#define GH 4

typedef float  f32x2  __attribute__((ext_vector_type(2)));
typedef float  f32x4  __attribute__((ext_vector_type(4)));
typedef float  f32x16 __attribute__((ext_vector_type(16)));
typedef __bf16 bf16x8 __attribute__((ext_vector_type(8)));

__device__ __forceinline__ float fast_exp2(float x) {
#if __has_builtin(__builtin_amdgcn_exp2f)
  return __builtin_amdgcn_exp2f(x);
#else
  return exp2f(x);
#endif
}

// ---------------- K1: wh GEMM (reads f32 directly, converts in-reg) ------
__global__ __launch_bounds__(256) void gat_wh(const float* __restrict__ hm,
                                              const float* __restrict__ wgt,
                                              const float* __restrict__ aw,
                                              __bf16* __restrict__ whT,
                                              float* __restrict__ lp2,
                                              float* __restrict__ lc2) {
  __shared__ float ldsC[64 * 132];
  const int t = threadIdx.x;
  const int wave = t >> 6, lane = t & 63;
  const int col = lane & 31, kg = lane >> 5;
  const int n0 = blockIdx.x * 64;
  const int rowHalf = (wave & 1) * 32;
  const int colBase = (wave >> 1) * 64;

  f32x16 acc[2];
#pragma unroll
  for (int ct = 0; ct < 2; ++ct)
#pragma unroll
    for (int i = 0; i < 16; ++i) acc[ct][i] = 0.0f;

#pragma unroll
  for (int kk = 0; kk < 8; ++kk) {
    const int k = kk * 16 + kg * 8;
    const f32x4 h0 = *(const f32x4*)(hm + (size_t)(n0 + rowHalf + col) * 128 + k);
    const f32x4 h1 = *(const f32x4*)(hm + (size_t)(n0 + rowHalf + col) * 128 + k + 4);
    bf16x8 af;
#pragma unroll
    for (int e = 0; e < 4; ++e) { af[e] = (__bf16)h0[e]; af[e + 4] = (__bf16)h1[e]; }
#pragma unroll
    for (int ct = 0; ct < 2; ++ct) {
      bf16x8 bfr;  // wgt column reads: coalesced across lanes
#pragma unroll
      for (int e = 0; e < 8; ++e)
        bfr[e] = (__bf16)wgt[(size_t)(k + e) * 128 + colBase + ct * 32 + col];
      acc[ct] = __builtin_amdgcn_mfma_f32_32x32x16_bf16(af, bfr, acc[ct], 0, 0, 0);
    }
  }
  // C layout (32x32): col = lane&31, row = (r&3) + 8*(r>>2) + 4*(lane>>5)
#pragma unroll
  for (int ct = 0; ct < 2; ++ct)
#pragma unroll
    for (int r = 0; r < 16; ++r)
      ldsC[(rowHalf + (r & 3) + 8 * (r >> 2) + 4 * kg) * 132 + colBase + ct * 32 + col] =
          acc[ct][r];
  __syncthreads();

  {  // transposed bf16 store: whT[feature][n]
    const int c = t >> 1, half = t & 1;
    __bf16* dst = whT + (size_t)c * GN + n0 + half * 32;
#pragma unroll
    for (int q = 0; q < 4; ++q) {
      bf16x8 v;
#pragma unroll
      for (int e = 0; e < 8; ++e) v[e] = (__bf16)ldsC[(half * 32 + q * 8 + e) * 132 + c];
      *(bf16x8*)(dst + q * 8) = v;
    }
  }
  {  // lp/lc dots, pre-scaled by log2(e)
    const int nl = t & 63, h = t >> 6;
    float sp = 0.f, sd = 0.f;
#pragma unroll
    for (int f = 0; f < 32; ++f) {
      const float v = ldsC[nl * 132 + h * 32 + f];
      sp = fmaf(v, aw[h * 64 + f], sp);
      sd = fmaf(v, aw[h * 64 + 32 + f], sd);
    }
    const float LOG2E = 1.4426950408889634f;
    lp2[(n0 + nl) * GH + h] = sp * LOG2E;
    lc2[(n0 + nl) * GH + h] = sd * LOG2E;
  }
}

// ---------------- K2: main fused masked-softmax-PV kernel ----------------
// 4 waves share the block's 16 rows, splitting its j-range 4-way; cross-wave
// combine via SEPARATE otile/dtile LDS (no aliasing — R6 lesson) and LDS
// atomics. (256,4): cap 128 VGPR, demand ~70 -> NO spill (R6's (256,8)
// forced-64 spill + graph replay produced divergent outputs + 3x slowdown).
template <int KS>
__global__ __launch_bounds__(256, 4) void gat_main(const float* __restrict__ adj,
                                                   const __bf16* __restrict__ whT,
                                                   const float* __restrict__ lp2,
                                                   const float* __restrict__ lc2,
                                                   float* __restrict__ pout,
                                                   float* __restrict__ pden) {
  constexpr int JR = GN / KS;          // block j-range (768 at KS=8)
  constexpr int WJR = JR / 4;          // per-wave j-range (192)
  constexpr int NITER = WJR / 32;      // 6
  __shared__ __align__(16) float lcs[GH][JR];      // 12 KB at KS=8
  __shared__ __align__(16) float otile[16][132];   // 8.25 KB
  __shared__ float dtile[16 * GH];                 // 256 B

  const int t = threadIdx.x;
  const int wave = t >> 6, lane = t & 63;
  const int r = lane & 15, jg = lane >> 4;
  const int nw = blockIdx.x * 16;      // block's 16 rows (shared by all waves)
  const int jbase = blockIdx.y * JR;

  for (int i = t; i < 16 * 132; i += 256) ((float*)otile)[i] = 0.f;
  if (t < 64) dtile[t] = 0.f;
  for (int i = t; i < JR; i += 256) {  // stage lc transposed: [h][j]
    const f32x4 v = *(const f32x4*)(lc2 + (size_t)(jbase + i) * GH);
    lcs[0][i] = v[0]; lcs[1][i] = v[1]; lcs[2][i] = v[2]; lcs[3][i] = v[3];
  }
  __syncthreads();                     // covers zero-init AND lcs staging

  const f32x4 lpv = *(const f32x4*)(lp2 + (size_t)(nw + r) * GH);

  f32x4 acc[GH][2];
#pragma unroll
  for (int h = 0; h < GH; ++h) {
    acc[h][0] = f32x4{0.f, 0.f, 0.f, 0.f};
    acc[h][1] = f32x4{0.f, 0.f, 0.f, 0.f};
  }
  float dreg[GH] = {0.f, 0.f, 0.f, 0.f};

  // this wave's j-quarter; iter tt reads abase + tt*32 floats (8 f32/lane)
  const float* abase = adj + (size_t)(nw + r) * GN + jbase + wave * WJR + jg * 8;

  f32x4 aA0 = *(const f32x4*)abase;
  f32x4 aA1 = *((const f32x4*)abase + 1);
  f32x4 aB0 = *(const f32x4*)(abase + 32);
  f32x4 aB1 = *((const f32x4*)(abase + 32) + 1);

  for (int tt = 0; tt < NITER; ++tt) {
    f32x4 aC0, aC1;
    if (tt + 2 < NITER) {              // depth-2 prefetch
      const float* ap = abase + (tt + 2) * 32;
      aC0 = *(const f32x4*)ap;
      aC1 = *((const f32x4*)ap + 1);
    }
    const int jl = wave * WJR + tt * 32 + jg * 8;   // local j in [0, JR)
    const __bf16* wp = whT + jbase + jl;
#pragma unroll
    for (int h = 0; h < GH; ++h) {
      const f32x4 lc0 = *(const f32x4*)&lcs[h][jl];
      const f32x4 lc1 = *(const f32x4*)&lcs[h][jl + 4];
      const bf16x8 b0 = *(const bf16x8*)(wp + (size_t)(h * 32 + r) * GN);
      const bf16x8 b1 = *(const bf16x8*)(wp + (size_t)(h * 32 + 16 + r) * GN);
      const f32x2 lph = f32x2{lpv[h], lpv[h]};
      bf16x8 afr;
#pragma unroll
      for (int p = 0; p < 4; ++p) {
        const f32x2 lcp = (p < 2) ? f32x2{lc0[2 * p], lc0[2 * p + 1]}
                                  : f32x2{lc1[2 * p - 4], lc1[2 * p - 3]};
        const f32x2 av  = (p < 2) ? f32x2{aA0[2 * p], aA0[2 * p + 1]}
                                  : f32x2{aA1[2 * p - 4], aA1[2 * p - 3]};
        const f32x2 x  = lph + lcp;
        const f32x2 xl = __builtin_elementwise_max(x, x * 0.2f);
        const f32x2 e  = av * f32x2{fast_exp2(xl[0]), fast_exp2(xl[1])};
        dreg[h] += e[0] + e[1];
        afr[2 * p]     = (__bf16)e[0];
        afr[2 * p + 1] = (__bf16)e[1];
      }
      acc[h][0] = __builtin_amdgcn_mfma_f32_16x16x32_bf16(afr, b0, acc[h][0], 0, 0, 0);
      acc[h][1] = __builtin_amdgcn_mfma_f32_16x16x32_bf16(afr, b1, acc[h][1], 0, 0, 0);
    }
    aA0 = aB0; aA1 = aB1; aB0 = aC0; aB1 = aC1;
  }

  // wave-local row denominator over jg groups (lanes r, r+16, r+32, r+48)
#pragma unroll
  for (int h = 0; h < GH; ++h) {
    float d = dreg[h];
    d += __shfl_xor(d, 16);
    d += __shfl_xor(d, 32);
    if (lane < 16) atomicAdd(&dtile[r * GH + h], d);
  }
  // cross-wave combine; C layout (16x16): col(f)=lane&15, row=jg*4+q
#pragma unroll
  for (int h = 0; h < GH; ++h)
#pragma unroll
    for (int hf = 0; hf < 2; ++hf)
#pragma unroll
      for (int q = 0; q < 4; ++q)
        atomicAdd(&otile[jg * 4 + q][h * 32 + hf * 16 + r], acc[h][hf][q]);
  __syncthreads();

  // coalesced partial stores (plain, no global atomics)
  float* pb = pout + ((size_t)blockIdx.y * GN + nw) * 128;
  for (int i = t; i < 512; i += 256) {
    const int row = i >> 5, cg = i & 31;
    *(f32x4*)(pb + row * 128 + cg * 4) = *(const f32x4*)&otile[row][cg * 4];
  }
  if (t < 16)
    *(f32x4*)(pden + ((size_t)blockIdx.y * GN + nw + t) * GH) =
        *(const f32x4*)&dtile[t * GH];
}

// ---------------- K3: combine partials + divide --------------------------
template <int KS>
__global__ __launch_bounds__(256) void gat_div(const float* __restrict__ pout,
                                               const float* __restrict__ pden,
                                               float* __restrict__ out) {
  const int idx = blockIdx.x * 256 + threadIdx.x;  // one f32x4 per thread
  const int n = idx >> 5;
  const int c0 = (idx & 31) * 4;
  const int h = c0 >> 5;
  f32x4 s = f32x4{0.f, 0.f, 0.f, 0.f};
  float den = 0.f;
#pragma unroll
  for (int y = 0; y < KS; ++y) {
    s += *(const f32x4*)(pout + (size_t)y * GN * 128 + (size_t)n * 128 + c0);
    den += pden[(size_t)y * GN * GH + (size_t)n * GH + h];
  }
  *(f32x4*)(out + (size_t)n * 128 + c0) = s * (1.0f / den);
}

extern "C" void kernel_launch(void* const* d_in, const int* in_sizes, int n_in,
                              void* d_out, int out_size, void* d_ws, size_t ws_size,
                              hipStream_t stream) {
  const float* hm  = (const float*)d_in[0];
  const float* adj = (const float*)d_in[1];
  const float* wgt = (const float*)d_in[2];
  const float* aw  = (const float*)d_in[3];
  float* out = (float*)d_out;

  char* ws = (char*)d_ws;
  __bf16* whT = (__bf16*)ws; ws += (size_t)128 * GN * 2;   // 1.5 MB
  float* lp2  = (float*)ws;  ws += GN * GH * 4;            // 96 KB
  float* lc2  = (float*)ws;  ws += GN * GH * 4;            // 96 KB
  float* pden = (float*)ws;                                // KS * 96 KB
  const size_t base = (size_t)(ws - (char*)d_ws);
  const size_t per_k = (size_t)GN * GH * 4 + (size_t)GN * 128 * 4;

  gat_wh<<<96, 256, 0, stream>>>(hm, wgt, aw, whT, lp2, lc2);

  if (ws_size >= base + 8 * per_k) {   // 27.7 MB (R5 proved ws >= 40.7 MB)
    float* pout = (float*)(ws + (size_t)8 * GN * GH * 4);
    gat_main<8><<<dim3(384, 8), 256, 0, stream>>>(adj, whT, lp2, lc2, pout, pden);
    gat_div<8><<<768, 256, 0, stream>>>(pout, pden, out);
  } else {
    float* pout = (float*)(ws + (size_t)4 * GN * GH * 4);
    gat_main<4><<<dim3(384, 4), 256, 0, stream>>>(adj, whT, lp2, lc2, pout, pden);
    gat_div<4><<<768, 256, 0, stream>>>(pout, pden, out);
  }
}

// Round 8
// 107.644 us; speedup vs baseline: 2.6627x; 2.6627x over previous
//
#include <hip/hip_runtime.h>
#include <hip/hip_bf16.h>
#include <stdint.h>
#include <stddef.h>

#define GN 6144
#define GH 4

typedef float  f32x2  __attribute__((ext_vector_type(2)));
typedef float  f32x4  __attribute__((ext_vector_type(4)));
typedef float  f32x16 __attribute__((ext_vector_type(16)));
typedef __bf16 bf16x8 __attribute__((ext_vector_type(8)));

__device__ __forceinline__ float fast_exp2(float x) {
#if __has_builtin(__builtin_amdgcn_exp2f)
  return __builtin_amdgcn_exp2f(x);
#else
  return exp2f(x);
#endif
}

// ---------------- K1: wh GEMM (reads f32 directly, converts in-reg) ------
__global__ __launch_bounds__(256) void gat_wh(const float* __restrict__ hm,
                                              const float* __restrict__ wgt,
                                              const float* __restrict__ aw,
                                              __bf16* __restrict__ whT,
                                              float* __restrict__ lp2,
                                              float* __restrict__ lc2) {
  __shared__ float ldsC[64 * 132];
  const int t = threadIdx.x;
  const int wave = t >> 6, lane = t & 63;
  const int col = lane & 31, kg = lane >> 5;
  const int n0 = blockIdx.x * 64;
  const int rowHalf = (wave & 1) * 32;
  const int colBase = (wave >> 1) * 64;

  f32x16 acc[2];
#pragma unroll
  for (int ct = 0; ct < 2; ++ct)
#pragma unroll
    for (int i = 0; i < 16; ++i) acc[ct][i] = 0.0f;

#pragma unroll
  for (int kk = 0; kk < 8; ++kk) {
    const int k = kk * 16 + kg * 8;
    const f32x4 h0 = *(const f32x4*)(hm + (size_t)(n0 + rowHalf + col) * 128 + k);
    const f32x4 h1 = *(const f32x4*)(hm + (size_t)(n0 + rowHalf + col) * 128 + k + 4);
    bf16x8 af;
#pragma unroll
    for (int e = 0; e < 4; ++e) { af[e] = (__bf16)h0[e]; af[e + 4] = (__bf16)h1[e]; }
#pragma unroll
    for (int ct = 0; ct < 2; ++ct) {
      bf16x8 bfr;  // wgt column reads: coalesced across lanes
#pragma unroll
      for (int e = 0; e < 8; ++e)
        bfr[e] = (__bf16)wgt[(size_t)(k + e) * 128 + colBase + ct * 32 + col];
      acc[ct] = __builtin_amdgcn_mfma_f32_32x32x16_bf16(af, bfr, acc[ct], 0, 0, 0);
    }
  }
  // C layout (32x32): col = lane&31, row = (r&3) + 8*(r>>2) + 4*(lane>>5)
#pragma unroll
  for (int ct = 0; ct < 2; ++ct)
#pragma unroll
    for (int r = 0; r < 16; ++r)
      ldsC[(rowHalf + (r & 3) + 8 * (r >> 2) + 4 * kg) * 132 + colBase + ct * 32 + col] =
          acc[ct][r];
  __syncthreads();

  {  // transposed bf16 store: whT[feature][n]
    const int c = t >> 1, half = t & 1;
    __bf16* dst = whT + (size_t)c * GN + n0 + half * 32;
#pragma unroll
    for (int q = 0; q < 4; ++q) {
      bf16x8 v;
#pragma unroll
      for (int e = 0; e < 8; ++e) v[e] = (__bf16)ldsC[(half * 32 + q * 8 + e) * 132 + c];
      *(bf16x8*)(dst + q * 8) = v;
    }
  }
  {  // lp/lc dots, pre-scaled by log2(e)
    const int nl = t & 63, h = t >> 6;
    float sp = 0.f, sd = 0.f;
#pragma unroll
    for (int f = 0; f < 32; ++f) {
      const float v = ldsC[nl * 132 + h * 32 + f];
      sp = fmaf(v, aw[h * 64 + f], sp);
      sd = fmaf(v, aw[h * 64 + 32 + f], sd);
    }
    const float LOG2E = 1.4426950408889634f;
    lp2[(n0 + nl) * GH + h] = sp * LOG2E;
    lc2[(n0 + nl) * GH + h] = sd * LOG2E;
  }
}

// ---------------- K2: main fused masked-softmax-PV kernel ----------------
// R5-proven structure (wave-owns-rows, direct-store epilogue, no cross-wave
// combine — R6/R7 fatter epilogues spilled). Changes: 128-thr blocks (finer
// scheduling granularity, 2.7x more blocks), depth-3 adj prefetch, f32x2 dreg.
template <int KS>
__global__ __launch_bounds__(128, 4) void gat_main(const float* __restrict__ adj,
                                                   const __bf16* __restrict__ whT,
                                                   const float* __restrict__ lp2,
                                                   const float* __restrict__ lc2,
                                                   float* __restrict__ pout,
                                                   float* __restrict__ pden) {
  constexpr int JR = GN / KS;          // block j-range (384 at KS=16)
  constexpr int NITER = JR / 32;       // 12 at KS=16
  __shared__ __align__(16) float lcs[GH][JR];   // 6 KB at KS=16

  const int t = threadIdx.x;
  const int wave = t >> 6, lane = t & 63;
  const int r = lane & 15, jg = lane >> 4;
  const int nw = blockIdx.x * 32 + wave * 16;   // this wave's 16 rows
  const int jbase = blockIdx.y * JR;

  for (int i = t; i < JR; i += 128) {  // stage lc transposed: [h][j]
    const f32x4 v = *(const f32x4*)(lc2 + (size_t)(jbase + i) * GH);
    lcs[0][i] = v[0]; lcs[1][i] = v[1]; lcs[2][i] = v[2]; lcs[3][i] = v[3];
  }
  __syncthreads();                     // only barrier in the kernel

  const f32x4 lpv = *(const f32x4*)(lp2 + (size_t)(nw + r) * GH);

  f32x4 acc[GH][2];
#pragma unroll
  for (int h = 0; h < GH; ++h) {
    acc[h][0] = f32x4{0.f, 0.f, 0.f, 0.f};
    acc[h][1] = f32x4{0.f, 0.f, 0.f, 0.f};
  }
  f32x2 dreg[GH];
#pragma unroll
  for (int h = 0; h < GH; ++h) dreg[h] = f32x2{0.f, 0.f};

  // adj row for this lane; iter tt reads abase + tt*32 floats (8 f32/lane)
  const float* abase = adj + (size_t)(nw + r) * GN + jbase + jg * 8;

  // depth-3 prefetch (~3 iters issue distance > ~900cyc HBM latency)
  f32x4 aA0 = *(const f32x4*)abase;
  f32x4 aA1 = *((const f32x4*)abase + 1);
  f32x4 aB0 = *(const f32x4*)(abase + 32);
  f32x4 aB1 = *((const f32x4*)(abase + 32) + 1);
  f32x4 aC0 = *(const f32x4*)(abase + 64);
  f32x4 aC1 = *((const f32x4*)(abase + 64) + 1);

  for (int tt = 0; tt < NITER; ++tt) {
    f32x4 aD0, aD1;
    if (tt + 3 < NITER) {
      const float* ap = abase + (tt + 3) * 32;
      aD0 = *(const f32x4*)ap;
      aD1 = *((const f32x4*)ap + 1);
    }
    const int jl = tt * 32 + jg * 8;   // local j in [0, JR)
    const __bf16* wp = whT + jbase + jl;
#pragma unroll
    for (int h = 0; h < GH; ++h) {
      const f32x4 lc0 = *(const f32x4*)&lcs[h][jl];
      const f32x4 lc1 = *(const f32x4*)&lcs[h][jl + 4];
      const bf16x8 b0 = *(const bf16x8*)(wp + (size_t)(h * 32 + r) * GN);
      const bf16x8 b1 = *(const bf16x8*)(wp + (size_t)(h * 32 + 16 + r) * GN);
      const f32x2 lph = f32x2{lpv[h], lpv[h]};
      bf16x8 afr;
#pragma unroll
      for (int p = 0; p < 4; ++p) {
        const f32x2 lcp = (p < 2) ? f32x2{lc0[2 * p], lc0[2 * p + 1]}
                                  : f32x2{lc1[2 * p - 4], lc1[2 * p - 3]};
        const f32x2 av  = (p < 2) ? f32x2{aA0[2 * p], aA0[2 * p + 1]}
                                  : f32x2{aA1[2 * p - 4], aA1[2 * p - 3]};
        const f32x2 x  = lph + lcp;
        const f32x2 xl = __builtin_elementwise_max(x, x * 0.2f);
        const f32x2 e  = av * f32x2{fast_exp2(xl[0]), fast_exp2(xl[1])};
        dreg[h] += e;
        afr[2 * p]     = (__bf16)e[0];
        afr[2 * p + 1] = (__bf16)e[1];
      }
      acc[h][0] = __builtin_amdgcn_mfma_f32_16x16x32_bf16(afr, b0, acc[h][0], 0, 0, 0);
      acc[h][1] = __builtin_amdgcn_mfma_f32_16x16x32_bf16(afr, b1, acc[h][1], 0, 0, 0);
    }
    aA0 = aB0; aA1 = aB1; aB0 = aC0; aB1 = aC1; aC0 = aD0; aC1 = aD1;
  }

  // row-denominator: reduce over jg groups (lanes r, r+16, r+32, r+48)
  float dsc[GH];
#pragma unroll
  for (int h = 0; h < GH; ++h) {
    float d = dreg[h][0] + dreg[h][1];
    d += __shfl_xor(d, 16);
    d += __shfl_xor(d, 32);
    dsc[h] = d;
  }
  if (lane < 16) {
    f32x4 dv = f32x4{dsc[0], dsc[1], dsc[2], dsc[3]};
    *(f32x4*)(pden + ((size_t)blockIdx.y * GN + nw + r) * GH) = dv;
  }
  // direct partial store; C layout (16x16): col(f)=lane&15, row=jg*4+q
  float* pb = pout + ((size_t)blockIdx.y * GN + nw) * 128;
#pragma unroll
  for (int h = 0; h < GH; ++h)
#pragma unroll
    for (int hf = 0; hf < 2; ++hf)
#pragma unroll
      for (int q = 0; q < 4; ++q)
        pb[(size_t)(jg * 4 + q) * 128 + h * 32 + hf * 16 + r] = acc[h][hf][q];
}

// ---------------- K3: combine partials + divide --------------------------
template <int KS>
__global__ __launch_bounds__(256) void gat_div(const float* __restrict__ pout,
                                               const float* __restrict__ pden,
                                               float* __restrict__ out) {
  const int idx = blockIdx.x * 256 + threadIdx.x;  // one f32x4 per thread
  const int n = idx >> 5;
  const int c0 = (idx & 31) * 4;
  const int h = c0 >> 5;
  f32x4 s = f32x4{0.f, 0.f, 0.f, 0.f};
  float den = 0.f;
#pragma unroll
  for (int y = 0; y < KS; ++y) {
    s += *(const f32x4*)(pout + (size_t)y * GN * 128 + (size_t)n * 128 + c0);
    den += pden[(size_t)y * GN * GH + (size_t)n * GH + h];
  }
  *(f32x4*)(out + (size_t)n * 128 + c0) = s * (1.0f / den);
}

extern "C" void kernel_launch(void* const* d_in, const int* in_sizes, int n_in,
                              void* d_out, int out_size, void* d_ws, size_t ws_size,
                              hipStream_t stream) {
  const float* hm  = (const float*)d_in[0];
  const float* adj = (const float*)d_in[1];
  const float* wgt = (const float*)d_in[2];
  const float* aw  = (const float*)d_in[3];
  float* out = (float*)d_out;

  char* ws = (char*)d_ws;
  __bf16* whT = (__bf16*)ws; ws += (size_t)128 * GN * 2;   // 1.5 MB
  float* lp2  = (float*)ws;  ws += GN * GH * 4;            // 96 KB
  float* lc2  = (float*)ws;  ws += GN * GH * 4;            // 96 KB
  float* pden = (float*)ws;                                // KS * 96 KB
  const size_t base = (size_t)(ws - (char*)d_ws);
  const size_t per_k = (size_t)GN * GH * 4 + (size_t)GN * 128 * 4;

  gat_wh<<<96, 256, 0, stream>>>(hm, wgt, aw, whT, lp2, lc2);

  if (ws_size >= base + 16 * per_k) {        // 53.7 MB
    float* pout = (float*)(ws + (size_t)16 * GN * GH * 4);
    gat_main<16><<<dim3(192, 16), 128, 0, stream>>>(adj, whT, lp2, lc2, pout, pden);
    gat_div<16><<<768, 256, 0, stream>>>(pout, pden, out);
  } else {                                   // 40.6 MB — proven to fit (R5)
    float* pout = (float*)(ws + (size_t)12 * GN * GH * 4);
    gat_main<12><<<dim3(192, 12), 128, 0, stream>>>(adj, whT, lp2, lc2, pout, pden);
    gat_div<12><<<768, 256, 0, stream>>>(pout, pden, out);
  }
}